// Round 1
// baseline (539.074 us; speedup 1.0000x reference)
//
#include <hip/hip_runtime.h>

#define N_PTS 16384
#define KNN   16
#define CIN   64
#define SDIM  8
#define CHUNK 4096
#define TILE  512

typedef __bf16 bf16x8 __attribute__((ext_vector_type(8)));
typedef float  f32x4  __attribute__((ext_vector_type(4)));

// ---------------- K1: s = x @ Ws^T + bs  (f64 master + f32 copy), sq = |s32|^2
__global__ __launch_bounds__(256) void k_proj(
    const float* __restrict__ x, const float* __restrict__ Ws, const float* __restrict__ bs,
    float* __restrict__ s32, double* __restrict__ s64, float* __restrict__ sq) {
  __shared__ double w[SDIM * CIN];
  __shared__ double bsh[SDIM];
  int tid = threadIdx.x;
  for (int t = tid; t < SDIM * CIN; t += 256) w[t] = (double)Ws[t];
  if (tid < SDIM) bsh[tid] = (double)bs[tid];
  __syncthreads();
  int i = blockIdx.x * 256 + tid;
  double acc[SDIM];
#pragma unroll
  for (int d = 0; d < SDIM; ++d) acc[d] = bsh[d];
  for (int j = 0; j < CIN; j += 4) {
    float4 xv = *(const float4*)(x + (size_t)i * CIN + j);
#pragma unroll
    for (int d = 0; d < SDIM; ++d) {
      acc[d] = fma((double)xv.x, w[d * CIN + j + 0], acc[d]);
      acc[d] = fma((double)xv.y, w[d * CIN + j + 1], acc[d]);
      acc[d] = fma((double)xv.z, w[d * CIN + j + 2], acc[d]);
      acc[d] = fma((double)xv.w, w[d * CIN + j + 3], acc[d]);
    }
  }
  float q = 0.f;
#pragma unroll
  for (int d = 0; d < SDIM; ++d) {
    float f = (float)acc[d];
    s64[(size_t)i * SDIM + d] = acc[d];
    s32[(size_t)i * SDIM + d] = f;
    q = fmaf(f, f, q);
  }
  sq[i] = q;
}

// ---------------- K2: chunked brute-force scan, per-lane sorted top-16 (packed keys)
// key = (f32 bits of clamped d2, top 18 bits) | candidate index (14 bits)
__global__ __launch_bounds__(256) void k_scan(
    const float* __restrict__ s32, const float* __restrict__ sq,
    unsigned short* __restrict__ partial) {
  __shared__ float tile[TILE * 12];  // per candidate: -2*s[0..7], sq, pad (48B stride, b128-aligned)
  int tid = threadIdx.x;
  int q = blockIdx.x * 256 + tid;
  int cbase = blockIdx.y * CHUNK;
  float si[8];
  float sqi = sq[q];
#pragma unroll
  for (int d = 0; d < 8; ++d) si[d] = s32[(size_t)q * 8 + d];
  unsigned kk[16];
#pragma unroll
  for (int r = 0; r < 16; ++r) kk[r] = 0xFFFFFFFFu;

  for (int t0 = 0; t0 < CHUNK; t0 += TILE) {
    __syncthreads();
    for (int r = tid; r < TILE; r += 256) {
      int j = cbase + t0 + r;
      float4 a = *(const float4*)(s32 + (size_t)j * 8);
      float4 b = *(const float4*)(s32 + (size_t)j * 8 + 4);
      tile[r * 12 + 0] = -2.f * a.x; tile[r * 12 + 1] = -2.f * a.y;
      tile[r * 12 + 2] = -2.f * a.z; tile[r * 12 + 3] = -2.f * a.w;
      tile[r * 12 + 4] = -2.f * b.x; tile[r * 12 + 5] = -2.f * b.y;
      tile[r * 12 + 6] = -2.f * b.z; tile[r * 12 + 7] = -2.f * b.w;
      tile[r * 12 + 8] = sq[j];
    }
    __syncthreads();
    for (int r = 0; r < TILE; ++r) {
      const float* row = tile + r * 12;
      float acc = sqi + row[8];
#pragma unroll
      for (int d = 0; d < 8; ++d) acc = fmaf(si[d], row[d], acc);
      acc = fmaxf(acc, 0.f);
      unsigned key = (__float_as_uint(acc) & 0xFFFFC000u) | (unsigned)(cbase + t0 + r);
      if (key < kk[15]) {  // sorted insert: kk ascending, kk[15] is current worst
#pragma unroll
        for (int rr = 15; rr > 0; --rr) kk[rr] = max(kk[rr - 1], min(kk[rr], key));
        kk[0] = min(kk[0], key);
      }
    }
  }
  unsigned short* p = partial + (size_t)q * 64 + blockIdx.y * 16;
#pragma unroll
  for (int r = 0; r < 16; ++r) p[r] = (unsigned short)(kk[r] & 0x3FFFu);
}

// ---------------- K3: exact f64 re-rank of the 64-candidate superset, bitonic sort, keep 16
__global__ __launch_bounds__(256) void k_merge(
    const double* __restrict__ s64, const unsigned short* __restrict__ partial,
    unsigned short* __restrict__ fin) {
  int lane = threadIdx.x & 63;
  int node = blockIdx.x * 4 + (threadIdx.x >> 6);
  int jc = partial[(size_t)node * 64 + lane];
  const double* si = s64 + (size_t)node * 8;
  const double* sj = s64 + (size_t)jc * 8;
  double d2 = 0.0;
#pragma unroll
  for (int d = 0; d < 8; ++d) { double t = si[d] - sj[d]; d2 = fma(t, t, d2); }
  unsigned long long key =
      (((unsigned long long)__double_as_longlong(d2)) & ~0x3FFFull) | (unsigned long long)jc;
#pragma unroll
  for (int size = 2; size <= 64; size <<= 1) {
#pragma unroll
    for (int stride = size >> 1; stride > 0; stride >>= 1) {
      unsigned lo = __shfl_xor((unsigned)key, stride, 64);
      unsigned hi = __shfl_xor((unsigned)(key >> 32), stride, 64);
      unsigned long long other = ((unsigned long long)hi << 32) | lo;
      bool takeMin = (((lane & size) == 0) == ((lane & stride) == 0));
      unsigned long long mn = key < other ? key : other;
      unsigned long long mx = key < other ? other : key;
      key = takeMin ? mn : mx;
    }
  }
  if (lane < 16) fin[(size_t)node * 16 + lane] = (unsigned short)(key & 0x3FFFull);
}

// ---------------- K4: gather + MLP (bf16 MFMA 16x16x32, f32 accum), LN, relu, mean over K
__device__ inline bf16x8 pack8(float4 a, float4 b) {
  bf16x8 r;
  r[0] = (__bf16)a.x; r[1] = (__bf16)a.y; r[2] = (__bf16)a.z; r[3] = (__bf16)a.w;
  r[4] = (__bf16)b.x; r[5] = (__bf16)b.y; r[6] = (__bf16)b.z; r[7] = (__bf16)b.w;
  return r;
}
__device__ inline float4 sub4(float4 a, float4 b) {
  return make_float4(a.x - b.x, a.y - b.y, a.z - b.z, a.w - b.w);
}
// LN over 64 channels of each edge-row, then affine + relu.
// acc[nt][j]: row (4*g + j), channel nt*16 + e  (C/D layout: col=lane&15, row=(lane>>4)*4+reg)
__device__ inline void ln_relu(const f32x4 acc[4], const float bc[4], const float gc[4],
                               const float bec[4], float nh[4][4]) {
#pragma unroll
  for (int j = 0; j < 4; ++j) {
    float v0 = acc[0][j] + bc[0], v1 = acc[1][j] + bc[1];
    float v2 = acc[2][j] + bc[2], v3 = acc[3][j] + bc[3];
    float t = v0 + v1 + v2 + v3;
    float qq = v0 * v0 + v1 * v1 + v2 * v2 + v3 * v3;
#pragma unroll
    for (int m = 1; m < 16; m <<= 1) {
      t += __shfl_xor(t, m, 64);
      qq += __shfl_xor(qq, m, 64);
    }
    float mean = t * (1.f / 64.f);
    float var = qq * (1.f / 64.f) - mean * mean;
    float rstd = rsqrtf(var + 1e-5f);
    nh[0][j] = fmaxf((v0 - mean) * rstd * gc[0] + bec[0], 0.f);
    nh[1][j] = fmaxf((v1 - mean) * rstd * gc[1] + bec[1], 0.f);
    nh[2][j] = fmaxf((v2 - mean) * rstd * gc[2] + bec[2], 0.f);
    nh[3][j] = fmaxf((v3 - mean) * rstd * gc[3] + bec[3], 0.f);
  }
}

__global__ __launch_bounds__(256) void k_mlp(
    const float* __restrict__ x, const unsigned short* __restrict__ nbr,
    const float* __restrict__ W1, const float* __restrict__ b1,
    const float* __restrict__ g1v, const float* __restrict__ be1,
    const float* __restrict__ W2, const float* __restrict__ b2,
    const float* __restrict__ g2v, const float* __restrict__ be2,
    float* __restrict__ out) {
  __shared__ float tr[4][16 * 68];
  const int lane = threadIdx.x & 63;
  const int wv = threadIdx.x >> 6;
  const int e = lane & 15;  // A row (edge) / B,C col (channel within tile)
  const int g = lane >> 4;  // k-group of 8

  // B fragments: lane holds B[k=(lane>>4)*8+u][col=lane&15]; B[k][c] = W^T[k][c] = W[c][k]
  bf16x8 B1[4][4];
#pragma unroll
  for (int ks = 0; ks < 4; ++ks)
#pragma unroll
    for (int nt = 0; nt < 4; ++nt) {
      const float* wr = W1 + (size_t)(nt * 16 + e) * 128 + ks * 32 + g * 8;
#pragma unroll
      for (int u = 0; u < 8; ++u) B1[ks][nt][u] = (__bf16)wr[u];
    }
  bf16x8 B2[2][4];
#pragma unroll
  for (int ks = 0; ks < 2; ++ks)
#pragma unroll
    for (int nt = 0; nt < 4; ++nt) {
      const float* wr = W2 + (size_t)(nt * 16 + e) * 64 + ks * 32 + g * 8;
#pragma unroll
      for (int u = 0; u < 8; ++u) B2[ks][nt][u] = (__bf16)wr[u];
    }
  float b1c[4], g1c[4], be1c[4], b2c[4], g2c[4], be2c[4];
#pragma unroll
  for (int nt = 0; nt < 4; ++nt) {
    int c = nt * 16 + e;
    b1c[nt] = b1[c]; g1c[nt] = g1v[c]; be1c[nt] = be1[c];
    b2c[nt] = b2[c]; g2c[nt] = g2v[c]; be2c[nt] = be2[c];
  }

  for (int it = 0; it < 8; ++it) {
    int node = (blockIdx.x * 4 + wv) * 8 + it;
    int jidx = nbr[(size_t)node * 16 + e];
    const float* xi = x + (size_t)node * 64;
    const float* xj = x + (size_t)jidx * 64;
    float4 xi0a = *(const float4*)(xi + g * 8),      xi0b = *(const float4*)(xi + g * 8 + 4);
    float4 xi1a = *(const float4*)(xi + 32 + g * 8), xi1b = *(const float4*)(xi + 32 + g * 8 + 4);
    float4 xj0a = *(const float4*)(xj + g * 8),      xj0b = *(const float4*)(xj + g * 8 + 4);
    float4 xj1a = *(const float4*)(xj + 32 + g * 8), xj1b = *(const float4*)(xj + 32 + g * 8 + 4);
    // feat = [x_i (k=0..63), x_j - x_i (k=64..127)]; A: lane holds A[row=e][k=ks*32+g*8+u]
    bf16x8 Af[4];
    Af[0] = pack8(xi0a, xi0b);
    Af[1] = pack8(xi1a, xi1b);
    Af[2] = pack8(sub4(xj0a, xi0a), sub4(xj0b, xi0b));
    Af[3] = pack8(sub4(xj1a, xi1a), sub4(xj1b, xi1b));

    f32x4 acc[4];
#pragma unroll
    for (int nt = 0; nt < 4; ++nt) acc[nt] = (f32x4){0.f, 0.f, 0.f, 0.f};
#pragma unroll
    for (int ks = 0; ks < 4; ++ks)
#pragma unroll
      for (int nt = 0; nt < 4; ++nt)
        acc[nt] = __builtin_amdgcn_mfma_f32_16x16x32_bf16(Af[ks], B1[ks][nt], acc[nt], 0, 0, 0);

    float nh[4][4];
    ln_relu(acc, b1c, g1c, be1c, nh);

    // transpose edge-major -> k-major via per-wave LDS tile
    float* T = tr[wv];
#pragma unroll
    for (int nt = 0; nt < 4; ++nt)
#pragma unroll
      for (int j = 0; j < 4; ++j) T[(4 * g + j) * 68 + nt * 16 + e] = nh[nt][j];
    __syncthreads();
    bf16x8 A2[2];
#pragma unroll
    for (int ks = 0; ks < 2; ++ks) {
      float4 ha = *(const float4*)(T + e * 68 + ks * 32 + g * 8);
      float4 hb = *(const float4*)(T + e * 68 + ks * 32 + g * 8 + 4);
      A2[ks] = pack8(ha, hb);
    }

    f32x4 acc2[4];
#pragma unroll
    for (int nt = 0; nt < 4; ++nt) acc2[nt] = (f32x4){0.f, 0.f, 0.f, 0.f};
#pragma unroll
    for (int ks = 0; ks < 2; ++ks)
#pragma unroll
      for (int nt = 0; nt < 4; ++nt)
        acc2[nt] = __builtin_amdgcn_mfma_f32_16x16x32_bf16(A2[ks], B2[ks][nt], acc2[nt], 0, 0, 0);

    float nh2[4][4];
    ln_relu(acc2, b2c, g2c, be2c, nh2);

    // mean over the 16 edge-rows
#pragma unroll
    for (int nt = 0; nt < 4; ++nt) {
      float p = nh2[nt][0] + nh2[nt][1] + nh2[nt][2] + nh2[nt][3];
      p += __shfl_xor(p, 16, 64);
      p += __shfl_xor(p, 32, 64);
      if (g == 0) out[(size_t)node * 64 + nt * 16 + e] = p * 0.0625f;
    }
    __syncthreads();
  }
}

extern "C" void kernel_launch(void* const* d_in, const int* in_sizes, int n_in,
                              void* d_out, int out_size, void* d_ws, size_t ws_size,
                              hipStream_t stream) {
  (void)in_sizes; (void)n_in; (void)out_size; (void)ws_size;
  const float* x   = (const float*)d_in[0];
  // d_in[1..3] = edge_index, eta, phi: unused by the reference computation
  const float* Ws  = (const float*)d_in[4];
  const float* bs  = (const float*)d_in[5];
  const float* W1  = (const float*)d_in[6];
  const float* b1  = (const float*)d_in[7];
  const float* g1  = (const float*)d_in[8];
  const float* be1 = (const float*)d_in[9];
  const float* W2  = (const float*)d_in[10];
  const float* b2  = (const float*)d_in[11];
  const float* g2  = (const float*)d_in[12];
  const float* be2 = (const float*)d_in[13];
  float* out = (float*)d_out;

  char* ws = (char*)d_ws;
  float*  s32 = (float*)(ws);                         // 16384*8*4   = 512KB
  float*  sq  = (float*)(ws + 524288);                // 16384*4     = 64KB
  double* s64 = (double*)(ws + 589824);               // 16384*8*8   = 1MB
  unsigned short* partial = (unsigned short*)(ws + 1638400);  // 16384*64*2 = 2MB
  unsigned short* fin     = (unsigned short*)(ws + 3735552);  // 16384*16*2 = 512KB

  k_proj<<<dim3(64), dim3(256), 0, stream>>>(x, Ws, bs, s32, s64, sq);
  k_scan<<<dim3(64, 4), dim3(256), 0, stream>>>(s32, sq, partial);
  k_merge<<<dim3(4096), dim3(256), 0, stream>>>(s64, partial, fin);
  k_mlp<<<dim3(512), dim3(256), 0, stream>>>(x, fin, W1, b1, g1, be1, W2, b2, g2, be2, out);
}

// Round 2
// 500.851 us; speedup vs baseline: 1.0763x; 1.0763x over previous
//
#include <hip/hip_runtime.h>

#define N_PTS 16384
#define KNN   16
#define CIN   64
#define SDIM  8
#define CHUNK 4096
#define TILE  128   // candidates staged per LDS tile (1-wave blocks)

typedef __bf16 bf16x8 __attribute__((ext_vector_type(8)));
typedef float  f32x4  __attribute__((ext_vector_type(4)));

// ---------------- K1: s = x @ Ws^T + bs  (f64 master + f32 copy), sq = |s32|^2
__global__ __launch_bounds__(256) void k_proj(
    const float* __restrict__ x, const float* __restrict__ Ws, const float* __restrict__ bs,
    float* __restrict__ s32, double* __restrict__ s64, float* __restrict__ sq) {
  __shared__ double w[SDIM * CIN];
  __shared__ double bsh[SDIM];
  int tid = threadIdx.x;
  for (int t = tid; t < SDIM * CIN; t += 256) w[t] = (double)Ws[t];
  if (tid < SDIM) bsh[tid] = (double)bs[tid];
  __syncthreads();
  int i = blockIdx.x * 256 + tid;
  double acc[SDIM];
#pragma unroll
  for (int d = 0; d < SDIM; ++d) acc[d] = bsh[d];
  for (int j = 0; j < CIN; j += 4) {
    float4 xv = *(const float4*)(x + (size_t)i * CIN + j);
#pragma unroll
    for (int d = 0; d < SDIM; ++d) {
      acc[d] = fma((double)xv.x, w[d * CIN + j + 0], acc[d]);
      acc[d] = fma((double)xv.y, w[d * CIN + j + 1], acc[d]);
      acc[d] = fma((double)xv.z, w[d * CIN + j + 2], acc[d]);
      acc[d] = fma((double)xv.w, w[d * CIN + j + 3], acc[d]);
    }
  }
  float q = 0.f;
#pragma unroll
  for (int d = 0; d < SDIM; ++d) {
    float f = (float)acc[d];
    s64[(size_t)i * SDIM + d] = acc[d];
    s32[(size_t)i * SDIM + d] = f;
    q = fmaf(f, f, q);
  }
  sq[i] = q;
}

// ---------------- K2: chunked brute-force scan, per-lane top-16 via threshold + LDS ring
// key = (f32 bits of clamped d2, top 18 bits) | candidate index (14 bits)
// 1-wave blocks (64 queries each), 16 blocks/CU (10KB LDS) -> ~50% occupancy.
// Accept path: cmp + masked ds_write + cnt++. The 32-op sorted-insert chain only runs
// in batched rebuilds (every ~13-16 accepts), killing the any-lane divergence tax.
__global__ __launch_bounds__(64) void k_scan(
    const float* __restrict__ s32, const float* __restrict__ sq,
    unsigned short* __restrict__ partial) {
  __shared__ float tile[TILE * 12];     // per candidate: -2*s[0..7], sq, pad (48B stride)
  __shared__ unsigned ring[16 * 64];    // ring[i*64 + lane]: conflict-free both ways
  const int lane = threadIdx.x;
  const int q = blockIdx.x * 64 + lane;
  const int cbase = blockIdx.y * CHUNK;

  float si[8];
  const float sqi = sq[q];
#pragma unroll
  for (int d = 0; d < 8; ++d) si[d] = s32[(size_t)q * 8 + d];

  unsigned kk[16];
#pragma unroll
  for (int r = 0; r < 16; ++r) kk[r] = 0xFFFFFFFFu;
  int cnt = 0;

  for (int t0 = 0; t0 < CHUNK; t0 += TILE) {
    __syncthreads();
#pragma unroll
    for (int r = lane; r < TILE; r += 64) {
      int j = cbase + t0 + r;
      float4 a = *(const float4*)(s32 + (size_t)j * 8);
      float4 b = *(const float4*)(s32 + (size_t)j * 8 + 4);
      *(float4*)(tile + r * 12 + 0) =
          make_float4(-2.f * a.x, -2.f * a.y, -2.f * a.z, -2.f * a.w);
      *(float4*)(tile + r * 12 + 4) =
          make_float4(-2.f * b.x, -2.f * b.y, -2.f * b.z, -2.f * b.w);
      tile[r * 12 + 8] = sq[j];
    }
    __syncthreads();

    for (int r = 0; r < TILE; r += 4) {
#pragma unroll
      for (int rr = 0; rr < 4; ++rr) {
        const float* row = tile + (r + rr) * 12;
        float4 ra = *(const float4*)(row);
        float4 rb = *(const float4*)(row + 4);
        float acc = sqi + row[8];
        acc = fmaf(si[0], ra.x, acc); acc = fmaf(si[1], ra.y, acc);
        acc = fmaf(si[2], ra.z, acc); acc = fmaf(si[3], ra.w, acc);
        acc = fmaf(si[4], rb.x, acc); acc = fmaf(si[5], rb.y, acc);
        acc = fmaf(si[6], rb.z, acc); acc = fmaf(si[7], rb.w, acc);
        acc = fmaxf(acc, 0.f);
        unsigned key = (__float_as_uint(acc) & 0xFFFFC000u) | (unsigned)(cbase + t0 + r + rr);
        if (key < kk[15]) {        // live threshold; ring defers the expensive insert
          ring[cnt * 64 + lane] = key;
          ++cnt;
        }
      }
      if (__any(cnt >= 13)) {      // cnt can grow by <=4 before next check => never >16
#pragma unroll 1
        for (int i = 0; i < 16; ++i) {
          if (!__any(i < cnt)) break;
          unsigned key = ring[i * 64 + lane];
          if (i >= cnt) key = 0xFFFFFFFFu;
          if (__any(key < kk[15])) {  // identity insert for key >= kk[15]
#pragma unroll
            for (int rr2 = 15; rr2 > 0; --rr2) kk[rr2] = max(kk[rr2 - 1], min(kk[rr2], key));
            kk[0] = min(kk[0], key);
          }
        }
        cnt = 0;
      }
    }
  }
  // final flush
#pragma unroll 1
  for (int i = 0; i < 16; ++i) {
    if (!__any(i < cnt)) break;
    unsigned key = ring[i * 64 + lane];
    if (i >= cnt) key = 0xFFFFFFFFu;
    if (__any(key < kk[15])) {
#pragma unroll
      for (int rr2 = 15; rr2 > 0; --rr2) kk[rr2] = max(kk[rr2 - 1], min(kk[rr2], key));
      kk[0] = min(kk[0], key);
    }
  }

  unsigned short* p = partial + (size_t)q * 64 + blockIdx.y * 16;
#pragma unroll
  for (int r = 0; r < 16; ++r) p[r] = (unsigned short)(kk[r] & 0x3FFFu);
}

// ---------------- K3: exact f64 re-rank of the 64-candidate superset, bitonic sort, keep 16
__global__ __launch_bounds__(256) void k_merge(
    const double* __restrict__ s64, const unsigned short* __restrict__ partial,
    unsigned short* __restrict__ fin) {
  int lane = threadIdx.x & 63;
  int node = blockIdx.x * 4 + (threadIdx.x >> 6);
  int jc = partial[(size_t)node * 64 + lane];
  const double* si = s64 + (size_t)node * 8;
  const double* sj = s64 + (size_t)jc * 8;
  double d2 = 0.0;
#pragma unroll
  for (int d = 0; d < 8; ++d) { double t = si[d] - sj[d]; d2 = fma(t, t, d2); }
  unsigned long long key =
      (((unsigned long long)__double_as_longlong(d2)) & ~0x3FFFull) | (unsigned long long)jc;
#pragma unroll
  for (int size = 2; size <= 64; size <<= 1) {
#pragma unroll
    for (int stride = size >> 1; stride > 0; stride >>= 1) {
      unsigned lo = __shfl_xor((unsigned)key, stride, 64);
      unsigned hi = __shfl_xor((unsigned)(key >> 32), stride, 64);
      unsigned long long other = ((unsigned long long)hi << 32) | lo;
      bool takeMin = (((lane & size) == 0) == ((lane & stride) == 0));
      unsigned long long mn = key < other ? key : other;
      unsigned long long mx = key < other ? other : key;
      key = takeMin ? mn : mx;
    }
  }
  if (lane < 16) fin[(size_t)node * 16 + lane] = (unsigned short)(key & 0x3FFFull);
}

// ---------------- K4: gather + MLP (bf16 MFMA 16x16x32, f32 accum), LN, relu, mean over K
__device__ inline bf16x8 pack8(float4 a, float4 b) {
  bf16x8 r;
  r[0] = (__bf16)a.x; r[1] = (__bf16)a.y; r[2] = (__bf16)a.z; r[3] = (__bf16)a.w;
  r[4] = (__bf16)b.x; r[5] = (__bf16)b.y; r[6] = (__bf16)b.z; r[7] = (__bf16)b.w;
  return r;
}
__device__ inline float4 sub4(float4 a, float4 b) {
  return make_float4(a.x - b.x, a.y - b.y, a.z - b.z, a.w - b.w);
}
// LN over 64 channels of each edge-row, then affine + relu.
// acc[nt][j]: row (4*g + j), channel nt*16 + e  (C/D layout: col=lane&15, row=(lane>>4)*4+reg)
__device__ inline void ln_relu(const f32x4 acc[4], const float bc[4], const float gc[4],
                               const float bec[4], float nh[4][4]) {
#pragma unroll
  for (int j = 0; j < 4; ++j) {
    float v0 = acc[0][j] + bc[0], v1 = acc[1][j] + bc[1];
    float v2 = acc[2][j] + bc[2], v3 = acc[3][j] + bc[3];
    float t = v0 + v1 + v2 + v3;
    float qq = v0 * v0 + v1 * v1 + v2 * v2 + v3 * v3;
#pragma unroll
    for (int m = 1; m < 16; m <<= 1) {
      t += __shfl_xor(t, m, 64);
      qq += __shfl_xor(qq, m, 64);
    }
    float mean = t * (1.f / 64.f);
    float var = qq * (1.f / 64.f) - mean * mean;
    float rstd = rsqrtf(var + 1e-5f);
    nh[0][j] = fmaxf((v0 - mean) * rstd * gc[0] + bec[0], 0.f);
    nh[1][j] = fmaxf((v1 - mean) * rstd * gc[1] + bec[1], 0.f);
    nh[2][j] = fmaxf((v2 - mean) * rstd * gc[2] + bec[2], 0.f);
    nh[3][j] = fmaxf((v3 - mean) * rstd * gc[3] + bec[3], 0.f);
  }
}

__global__ __launch_bounds__(256) void k_mlp(
    const float* __restrict__ x, const unsigned short* __restrict__ nbr,
    const float* __restrict__ W1, const float* __restrict__ b1,
    const float* __restrict__ g1v, const float* __restrict__ be1,
    const float* __restrict__ W2, const float* __restrict__ b2,
    const float* __restrict__ g2v, const float* __restrict__ be2,
    float* __restrict__ out) {
  __shared__ float tr[4][16 * 68];
  const int lane = threadIdx.x & 63;
  const int wv = threadIdx.x >> 6;
  const int e = lane & 15;  // A row (edge) / B,C col (channel within tile)
  const int g = lane >> 4;  // k-group of 8

  // B fragments: lane holds B[k=(lane>>4)*8+u][col=lane&15]; B[k][c] = W^T[k][c] = W[c][k]
  bf16x8 B1[4][4];
#pragma unroll
  for (int ks = 0; ks < 4; ++ks)
#pragma unroll
    for (int nt = 0; nt < 4; ++nt) {
      const float* wr = W1 + (size_t)(nt * 16 + e) * 128 + ks * 32 + g * 8;
#pragma unroll
      for (int u = 0; u < 8; ++u) B1[ks][nt][u] = (__bf16)wr[u];
    }
  bf16x8 B2[2][4];
#pragma unroll
  for (int ks = 0; ks < 2; ++ks)
#pragma unroll
    for (int nt = 0; nt < 4; ++nt) {
      const float* wr = W2 + (size_t)(nt * 16 + e) * 64 + ks * 32 + g * 8;
#pragma unroll
      for (int u = 0; u < 8; ++u) B2[ks][nt][u] = (__bf16)wr[u];
    }
  float b1c[4], g1c[4], be1c[4], b2c[4], g2c[4], be2c[4];
#pragma unroll
  for (int nt = 0; nt < 4; ++nt) {
    int c = nt * 16 + e;
    b1c[nt] = b1[c]; g1c[nt] = g1v[c]; be1c[nt] = be1[c];
    b2c[nt] = b2[c]; g2c[nt] = g2v[c]; be2c[nt] = be2[c];
  }

  for (int it = 0; it < 8; ++it) {
    int node = (blockIdx.x * 4 + wv) * 8 + it;
    int jidx = nbr[(size_t)node * 16 + e];
    const float* xi = x + (size_t)node * 64;
    const float* xj = x + (size_t)jidx * 64;
    float4 xi0a = *(const float4*)(xi + g * 8),      xi0b = *(const float4*)(xi + g * 8 + 4);
    float4 xi1a = *(const float4*)(xi + 32 + g * 8), xi1b = *(const float4*)(xi + 32 + g * 8 + 4);
    float4 xj0a = *(const float4*)(xj + g * 8),      xj0b = *(const float4*)(xj + g * 8 + 4);
    float4 xj1a = *(const float4*)(xj + 32 + g * 8), xj1b = *(const float4*)(xj + 32 + g * 8 + 4);
    // feat = [x_i (k=0..63), x_j - x_i (k=64..127)]; A: lane holds A[row=e][k=ks*32+g*8+u]
    bf16x8 Af[4];
    Af[0] = pack8(xi0a, xi0b);
    Af[1] = pack8(xi1a, xi1b);
    Af[2] = pack8(sub4(xj0a, xi0a), sub4(xj0b, xi0b));
    Af[3] = pack8(sub4(xj1a, xi1a), sub4(xj1b, xi1b));

    f32x4 acc[4];
#pragma unroll
    for (int nt = 0; nt < 4; ++nt) acc[nt] = (f32x4){0.f, 0.f, 0.f, 0.f};
#pragma unroll
    for (int ks = 0; ks < 4; ++ks)
#pragma unroll
      for (int nt = 0; nt < 4; ++nt)
        acc[nt] = __builtin_amdgcn_mfma_f32_16x16x32_bf16(Af[ks], B1[ks][nt], acc[nt], 0, 0, 0);

    float nh[4][4];
    ln_relu(acc, b1c, g1c, be1c, nh);

    // transpose edge-major -> k-major via per-wave LDS tile
    float* T = tr[wv];
#pragma unroll
    for (int nt = 0; nt < 4; ++nt)
#pragma unroll
      for (int j = 0; j < 4; ++j) T[(4 * g + j) * 68 + nt * 16 + e] = nh[nt][j];
    __syncthreads();
    bf16x8 A2[2];
#pragma unroll
    for (int ks = 0; ks < 2; ++ks) {
      float4 ha = *(const float4*)(T + e * 68 + ks * 32 + g * 8);
      float4 hb = *(const float4*)(T + e * 68 + ks * 32 + g * 8 + 4);
      A2[ks] = pack8(ha, hb);
    }

    f32x4 acc2[4];
#pragma unroll
    for (int nt = 0; nt < 4; ++nt) acc2[nt] = (f32x4){0.f, 0.f, 0.f, 0.f};
#pragma unroll
    for (int ks = 0; ks < 2; ++ks)
#pragma unroll
      for (int nt = 0; nt < 4; ++nt)
        acc2[nt] = __builtin_amdgcn_mfma_f32_16x16x32_bf16(A2[ks], B2[ks][nt], acc2[nt], 0, 0, 0);

    float nh2[4][4];
    ln_relu(acc2, b2c, g2c, be2c, nh2);

    // mean over the 16 edge-rows
#pragma unroll
    for (int nt = 0; nt < 4; ++nt) {
      float p = nh2[nt][0] + nh2[nt][1] + nh2[nt][2] + nh2[nt][3];
      p += __shfl_xor(p, 16, 64);
      p += __shfl_xor(p, 32, 64);
      if (g == 0) out[(size_t)node * 64 + nt * 16 + e] = p * 0.0625f;
    }
    __syncthreads();
  }
}

extern "C" void kernel_launch(void* const* d_in, const int* in_sizes, int n_in,
                              void* d_out, int out_size, void* d_ws, size_t ws_size,
                              hipStream_t stream) {
  (void)in_sizes; (void)n_in; (void)out_size; (void)ws_size;
  const float* x   = (const float*)d_in[0];
  // d_in[1..3] = edge_index, eta, phi: unused by the reference computation
  const float* Ws  = (const float*)d_in[4];
  const float* bs  = (const float*)d_in[5];
  const float* W1  = (const float*)d_in[6];
  const float* b1  = (const float*)d_in[7];
  const float* g1  = (const float*)d_in[8];
  const float* be1 = (const float*)d_in[9];
  const float* W2  = (const float*)d_in[10];
  const float* b2  = (const float*)d_in[11];
  const float* g2  = (const float*)d_in[12];
  const float* be2 = (const float*)d_in[13];
  float* out = (float*)d_out;

  char* ws = (char*)d_ws;
  float*  s32 = (float*)(ws);                         // 16384*8*4   = 512KB
  float*  sq  = (float*)(ws + 524288);                // 16384*4     = 64KB
  double* s64 = (double*)(ws + 589824);               // 16384*8*8   = 1MB
  unsigned short* partial = (unsigned short*)(ws + 1638400);  // 16384*64*2 = 2MB
  unsigned short* fin     = (unsigned short*)(ws + 3735552);  // 16384*16*2 = 512KB

  k_proj<<<dim3(64), dim3(256), 0, stream>>>(x, Ws, bs, s32, s64, sq);
  k_scan<<<dim3(256, 4), dim3(64), 0, stream>>>(s32, sq, partial);
  k_merge<<<dim3(4096), dim3(256), 0, stream>>>(s64, partial, fin);
  k_mlp<<<dim3(512), dim3(256), 0, stream>>>(x, fin, W1, b1, g1, be1, W2, b2, g2, be2, out);
}

// Round 3
// 336.243 us; speedup vs baseline: 1.6032x; 1.4895x over previous
//
#include <hip/hip_runtime.h>

#define N_PTS 16384
#define KNN   16
#define CIN   64
#define SDIM  8
#define NCHUNK 16
#define CHUNK  1024

typedef __bf16 bf16x8 __attribute__((ext_vector_type(8)));
typedef float  f32x4  __attribute__((ext_vector_type(4)));

// ---------------- K1: s = x @ Ws^T + bs (f64 master), s2 = -2*s (f32), sq = |s|^2 (f32)
__global__ __launch_bounds__(256) void k_proj(
    const float* __restrict__ x, const float* __restrict__ Ws, const float* __restrict__ bs,
    float* __restrict__ s2, double* __restrict__ s64, float* __restrict__ sq) {
  __shared__ double w[SDIM * CIN];
  __shared__ double bsh[SDIM];
  int tid = threadIdx.x;
  for (int t = tid; t < SDIM * CIN; t += 256) w[t] = (double)Ws[t];
  if (tid < SDIM) bsh[tid] = (double)bs[tid];
  __syncthreads();
  int i = blockIdx.x * 256 + tid;
  double acc[SDIM];
#pragma unroll
  for (int d = 0; d < SDIM; ++d) acc[d] = bsh[d];
  for (int j = 0; j < CIN; j += 4) {
    float4 xv = *(const float4*)(x + (size_t)i * CIN + j);
#pragma unroll
    for (int d = 0; d < SDIM; ++d) {
      acc[d] = fma((double)xv.x, w[d * CIN + j + 0], acc[d]);
      acc[d] = fma((double)xv.y, w[d * CIN + j + 1], acc[d]);
      acc[d] = fma((double)xv.z, w[d * CIN + j + 2], acc[d]);
      acc[d] = fma((double)xv.w, w[d * CIN + j + 3], acc[d]);
    }
  }
  float q = 0.f;
#pragma unroll
  for (int d = 0; d < SDIM; ++d) {
    float f = (float)acc[d];
    s64[(size_t)i * SDIM + d] = acc[d];
    s2[(size_t)i * SDIM + d] = -2.f * f;
    q = fmaf(f, f, q);
  }
  sq[i] = q;
}

// ---------------- K2: brute-force scan; wave-uniform global reads (L1/L2 broadcast),
// per-lane top-16 via float threshold + deferred LDS-ring insert.
// key = (f32 bits of clamped d2, top 18 bits) | candidate index (14 bits)
__global__ __launch_bounds__(64) void k_scan(
    const float* __restrict__ s2, const float* __restrict__ sq,
    unsigned* __restrict__ partial) {
  __shared__ unsigned ring[16 * 64];  // ring[i*64+lane]: conflict-free
  const int lane = threadIdx.x;
  const int q = blockIdx.x * 64 + lane;
  const int cbase = blockIdx.y * CHUNK;

  float si[8];
#pragma unroll
  for (int d = 0; d < 8; ++d) si[d] = -0.5f * s2[(size_t)q * 8 + d];  // exact: si = s_i (f32)
  const float sqi = sq[q];

  unsigned kk[16];
#pragma unroll
  for (int r = 0; r < 16; ++r) kk[r] = 0xFFFFFFFFu;
  float thrF = __uint_as_float(0x7F800000u);  // +inf
  int cnt = 0;

  for (int t0 = 0; t0 < CHUNK; t0 += 4) {
#pragma unroll
    for (int rr = 0; rr < 4; ++rr) {
      const int j = cbase + t0 + rr;
      const float* row = s2 + (size_t)j * 8;   // wave-uniform address -> broadcast
      float4 ra = *(const float4*)(row);
      float4 rb = *(const float4*)(row + 4);
      float acc = sqi + sq[j];
      acc = fmaf(si[0], ra.x, acc); acc = fmaf(si[1], ra.y, acc);
      acc = fmaf(si[2], ra.z, acc); acc = fmaf(si[3], ra.w, acc);
      acc = fmaf(si[4], rb.x, acc); acc = fmaf(si[5], rb.y, acc);
      acc = fmaf(si[6], rb.z, acc); acc = fmaf(si[7], rb.w, acc);
      if (acc < thrF) {  // conservative float threshold (covers key-tie bucket)
        float ac = fmaxf(acc, 0.f);
        unsigned key = (__float_as_uint(ac) & 0xFFFFC000u) | (unsigned)j;
        ring[cnt * 64 + lane] = key;
        ++cnt;
      }
    }
    if (__any(cnt >= 13)) {  // cnt grows <=4 between checks => never >16
#pragma unroll 1
      for (int i = 0; i < 16; ++i) {
        if (!__any(i < cnt)) break;
        unsigned key = ring[i * 64 + lane];
        if (i >= cnt) key = 0xFFFFFFFFu;
        if (__any(key < kk[15])) {  // identity insert for key >= kk[15]
#pragma unroll
          for (int rr2 = 15; rr2 > 0; --rr2) kk[rr2] = max(kk[rr2 - 1], min(kk[rr2], key));
          kk[0] = min(kk[0], key);
        }
      }
      cnt = 0;
      unsigned tb = min((kk[15] >> 14) + 1u, 0x1FE00u);  // saturate; UINT_MAX -> +inf
      thrF = __uint_as_float(tb << 14);
    }
  }
  // final flush
#pragma unroll 1
  for (int i = 0; i < 16; ++i) {
    if (!__any(i < cnt)) break;
    unsigned key = ring[i * 64 + lane];
    if (i >= cnt) key = 0xFFFFFFFFu;
    if (__any(key < kk[15])) {
#pragma unroll
      for (int rr2 = 15; rr2 > 0; --rr2) kk[rr2] = max(kk[rr2 - 1], min(kk[rr2], key));
      kk[0] = min(kk[0], key);
    }
  }

  unsigned* p = partial + (size_t)q * 256 + blockIdx.y * 16;
#pragma unroll
  for (int r = 0; r < 16; ++r) p[r] = kk[r];
}

// ---------------- K2.5: reduce 256 keyed candidates -> 64 (4 layer-wise bitonic-64 sorts)
__global__ __launch_bounds__(256) void k_reduce(
    const unsigned* __restrict__ partial, unsigned short* __restrict__ cand64) {
  int lane = threadIdx.x & 63;
  int q = blockIdx.x * 4 + (threadIdx.x >> 6);
#pragma unroll
  for (int t = 0; t < 4; ++t) {
    unsigned key = partial[(size_t)q * 256 + t * 64 + lane];
#pragma unroll
    for (int size = 2; size <= 64; size <<= 1) {
#pragma unroll
      for (int stride = size >> 1; stride > 0; stride >>= 1) {
        unsigned other = __shfl_xor(key, stride, 64);
        bool takeMin = (((lane & size) == 0) == ((lane & stride) == 0));
        unsigned mn = min(key, other), mx = max(key, other);
        key = takeMin ? mn : mx;
      }
    }
    if (lane < 16) cand64[(size_t)q * 64 + t * 16 + lane] = (unsigned short)(key & 0x3FFFu);
  }
}

// ---------------- K3: exact f64 re-rank of the 64-candidate superset, bitonic sort, keep 16
__global__ __launch_bounds__(256) void k_merge(
    const double* __restrict__ s64, const unsigned short* __restrict__ cand64,
    unsigned short* __restrict__ fin) {
  int lane = threadIdx.x & 63;
  int node = blockIdx.x * 4 + (threadIdx.x >> 6);
  int jc = cand64[(size_t)node * 64 + lane];
  const double* si = s64 + (size_t)node * 8;
  const double* sj = s64 + (size_t)jc * 8;
  double d2 = 0.0;
#pragma unroll
  for (int d = 0; d < 8; ++d) { double t = si[d] - sj[d]; d2 = fma(t, t, d2); }
  unsigned long long key =
      (((unsigned long long)__double_as_longlong(d2)) & ~0x3FFFull) | (unsigned long long)jc;
#pragma unroll
  for (int size = 2; size <= 64; size <<= 1) {
#pragma unroll
    for (int stride = size >> 1; stride > 0; stride >>= 1) {
      unsigned lo = __shfl_xor((unsigned)key, stride, 64);
      unsigned hi = __shfl_xor((unsigned)(key >> 32), stride, 64);
      unsigned long long other = ((unsigned long long)hi << 32) | lo;
      bool takeMin = (((lane & size) == 0) == ((lane & stride) == 0));
      unsigned long long mn = key < other ? key : other;
      unsigned long long mx = key < other ? other : key;
      key = takeMin ? mn : mx;
    }
  }
  if (lane < 16) fin[(size_t)node * 16 + lane] = (unsigned short)(key & 0x3FFFull);
}

// ---------------- K4: gather + MLP (bf16 MFMA 16x16x32, f32 accum), LN, relu, mean over K
__device__ inline bf16x8 pack8(float4 a, float4 b) {
  bf16x8 r;
  r[0] = (__bf16)a.x; r[1] = (__bf16)a.y; r[2] = (__bf16)a.z; r[3] = (__bf16)a.w;
  r[4] = (__bf16)b.x; r[5] = (__bf16)b.y; r[6] = (__bf16)b.z; r[7] = (__bf16)b.w;
  return r;
}
__device__ inline float4 sub4(float4 a, float4 b) {
  return make_float4(a.x - b.x, a.y - b.y, a.z - b.z, a.w - b.w);
}
// LN over 64 channels of each edge-row, then affine + relu.
// acc[nt][j]: row (4*g + j), channel nt*16 + e  (C/D layout: col=lane&15, row=(lane>>4)*4+reg)
__device__ inline void ln_relu(const f32x4 acc[4], const float bc[4], const float gc[4],
                               const float bec[4], float nh[4][4]) {
#pragma unroll
  for (int j = 0; j < 4; ++j) {
    float v0 = acc[0][j] + bc[0], v1 = acc[1][j] + bc[1];
    float v2 = acc[2][j] + bc[2], v3 = acc[3][j] + bc[3];
    float t = v0 + v1 + v2 + v3;
    float qq = v0 * v0 + v1 * v1 + v2 * v2 + v3 * v3;
#pragma unroll
    for (int m = 1; m < 16; m <<= 1) {
      t += __shfl_xor(t, m, 64);
      qq += __shfl_xor(qq, m, 64);
    }
    float mean = t * (1.f / 64.f);
    float var = qq * (1.f / 64.f) - mean * mean;
    float rstd = rsqrtf(var + 1e-5f);
    nh[0][j] = fmaxf((v0 - mean) * rstd * gc[0] + bec[0], 0.f);
    nh[1][j] = fmaxf((v1 - mean) * rstd * gc[1] + bec[1], 0.f);
    nh[2][j] = fmaxf((v2 - mean) * rstd * gc[2] + bec[2], 0.f);
    nh[3][j] = fmaxf((v3 - mean) * rstd * gc[3] + bec[3], 0.f);
  }
}

__global__ __launch_bounds__(256) void k_mlp(
    const float* __restrict__ x, const unsigned short* __restrict__ nbr,
    const float* __restrict__ W1, const float* __restrict__ b1,
    const float* __restrict__ g1v, const float* __restrict__ be1,
    const float* __restrict__ W2, const float* __restrict__ b2,
    const float* __restrict__ g2v, const float* __restrict__ be2,
    float* __restrict__ out) {
  __shared__ float tr[4][16 * 68];
  const int lane = threadIdx.x & 63;
  const int wv = threadIdx.x >> 6;
  const int e = lane & 15;  // A row (edge) / B,C col (channel within tile)
  const int g = lane >> 4;  // k-group of 8

  // B fragments: lane holds B[k=(lane>>4)*8+u][col=lane&15]; B[k][c] = W^T[k][c] = W[c][k]
  bf16x8 B1[4][4];
#pragma unroll
  for (int ks = 0; ks < 4; ++ks)
#pragma unroll
    for (int nt = 0; nt < 4; ++nt) {
      const float* wr = W1 + (size_t)(nt * 16 + e) * 128 + ks * 32 + g * 8;
#pragma unroll
      for (int u = 0; u < 8; ++u) B1[ks][nt][u] = (__bf16)wr[u];
    }
  bf16x8 B2[2][4];
#pragma unroll
  for (int ks = 0; ks < 2; ++ks)
#pragma unroll
    for (int nt = 0; nt < 4; ++nt) {
      const float* wr = W2 + (size_t)(nt * 16 + e) * 64 + ks * 32 + g * 8;
#pragma unroll
      for (int u = 0; u < 8; ++u) B2[ks][nt][u] = (__bf16)wr[u];
    }
  float b1c[4], g1c[4], be1c[4], b2c[4], g2c[4], be2c[4];
#pragma unroll
  for (int nt = 0; nt < 4; ++nt) {
    int c = nt * 16 + e;
    b1c[nt] = b1[c]; g1c[nt] = g1v[c]; be1c[nt] = be1[c];
    b2c[nt] = b2[c]; g2c[nt] = g2v[c]; be2c[nt] = be2[c];
  }

  for (int it = 0; it < 8; ++it) {
    int node = (blockIdx.x * 4 + wv) * 8 + it;
    int jidx = nbr[(size_t)node * 16 + e];
    const float* xi = x + (size_t)node * 64;
    const float* xj = x + (size_t)jidx * 64;
    float4 xi0a = *(const float4*)(xi + g * 8),      xi0b = *(const float4*)(xi + g * 8 + 4);
    float4 xi1a = *(const float4*)(xi + 32 + g * 8), xi1b = *(const float4*)(xi + 32 + g * 8 + 4);
    float4 xj0a = *(const float4*)(xj + g * 8),      xj0b = *(const float4*)(xj + g * 8 + 4);
    float4 xj1a = *(const float4*)(xj + 32 + g * 8), xj1b = *(const float4*)(xj + 32 + g * 8 + 4);
    // feat = [x_i (k=0..63), x_j - x_i (k=64..127)]; A: lane holds A[row=e][k=ks*32+g*8+u]
    bf16x8 Af[4];
    Af[0] = pack8(xi0a, xi0b);
    Af[1] = pack8(xi1a, xi1b);
    Af[2] = pack8(sub4(xj0a, xi0a), sub4(xj0b, xi0b));
    Af[3] = pack8(sub4(xj1a, xi1a), sub4(xj1b, xi1b));

    f32x4 acc[4];
#pragma unroll
    for (int nt = 0; nt < 4; ++nt) acc[nt] = (f32x4){0.f, 0.f, 0.f, 0.f};
#pragma unroll
    for (int ks = 0; ks < 4; ++ks)
#pragma unroll
      for (int nt = 0; nt < 4; ++nt)
        acc[nt] = __builtin_amdgcn_mfma_f32_16x16x32_bf16(Af[ks], B1[ks][nt], acc[nt], 0, 0, 0);

    float nh[4][4];
    ln_relu(acc, b1c, g1c, be1c, nh);

    // transpose edge-major -> k-major via per-wave LDS tile
    float* T = tr[wv];
#pragma unroll
    for (int nt = 0; nt < 4; ++nt)
#pragma unroll
      for (int j = 0; j < 4; ++j) T[(4 * g + j) * 68 + nt * 16 + e] = nh[nt][j];
    __syncthreads();
    bf16x8 A2[2];
#pragma unroll
    for (int ks = 0; ks < 2; ++ks) {
      float4 ha = *(const float4*)(T + e * 68 + ks * 32 + g * 8);
      float4 hb = *(const float4*)(T + e * 68 + ks * 32 + g * 8 + 4);
      A2[ks] = pack8(ha, hb);
    }

    f32x4 acc2[4];
#pragma unroll
    for (int nt = 0; nt < 4; ++nt) acc2[nt] = (f32x4){0.f, 0.f, 0.f, 0.f};
#pragma unroll
    for (int ks = 0; ks < 2; ++ks)
#pragma unroll
      for (int nt = 0; nt < 4; ++nt)
        acc2[nt] = __builtin_amdgcn_mfma_f32_16x16x32_bf16(A2[ks], B2[ks][nt], acc2[nt], 0, 0, 0);

    float nh2[4][4];
    ln_relu(acc2, b2c, g2c, be2c, nh2);

    // mean over the 16 edge-rows
#pragma unroll
    for (int nt = 0; nt < 4; ++nt) {
      float p = nh2[nt][0] + nh2[nt][1] + nh2[nt][2] + nh2[nt][3];
      p += __shfl_xor(p, 16, 64);
      p += __shfl_xor(p, 32, 64);
      if (g == 0) out[(size_t)node * 64 + nt * 16 + e] = p * 0.0625f;
    }
    __syncthreads();
  }
}

extern "C" void kernel_launch(void* const* d_in, const int* in_sizes, int n_in,
                              void* d_out, int out_size, void* d_ws, size_t ws_size,
                              hipStream_t stream) {
  (void)in_sizes; (void)n_in; (void)out_size; (void)ws_size;
  const float* x   = (const float*)d_in[0];
  // d_in[1..3] = edge_index, eta, phi: unused by the reference computation
  const float* Ws  = (const float*)d_in[4];
  const float* bs  = (const float*)d_in[5];
  const float* W1  = (const float*)d_in[6];
  const float* b1  = (const float*)d_in[7];
  const float* g1  = (const float*)d_in[8];
  const float* be1 = (const float*)d_in[9];
  const float* W2  = (const float*)d_in[10];
  const float* b2  = (const float*)d_in[11];
  const float* g2  = (const float*)d_in[12];
  const float* be2 = (const float*)d_in[13];
  float* out = (float*)d_out;

  char* ws = (char*)d_ws;
  float*  s2  = (float*)(ws);                           // 16384*8*4   = 512KB
  float*  sq  = (float*)(ws + 524288);                  // 16384*4     = 64KB
  double* s64 = (double*)(ws + 589824);                 // 16384*8*8   = 1MB -> ends 1638400
  unsigned* partial      = (unsigned*)(ws + 1638400);   // 16384*256*4 = 16MB -> ends 18415616
  unsigned short* cand64 = (unsigned short*)(ws + 18415616);  // 16384*64*2 = 2MB -> 20512768
  unsigned short* fin    = (unsigned short*)(ws + 20512768);  // 16384*16*2 = 512KB

  k_proj<<<dim3(64), dim3(256), 0, stream>>>(x, Ws, bs, s2, s64, sq);
  k_scan<<<dim3(256, NCHUNK), dim3(64), 0, stream>>>(s2, sq, partial);
  k_reduce<<<dim3(4096), dim3(256), 0, stream>>>(partial, cand64);
  k_merge<<<dim3(4096), dim3(256), 0, stream>>>(s64, cand64, fin);
  k_mlp<<<dim3(512), dim3(256), 0, stream>>>(x, fin, W1, b1, g1, be1, W2, b2, g2, be2, out);
}